// Round 1
// baseline (3585.796 us; speedup 1.0000x reference)
//
#include <hip/hip_runtime.h>
#include <math.h>

#define BATCH 10
#define HID 128
#define OUT 7
#define MAXLEN 2048
#define NG (4*HID)          // 512 gates
#define WOUT_STRIDE 132     // pad 128 -> 132 to avoid LDS bank conflicts

__device__ __forceinline__ float sigmoidf_(float x) { return 1.0f / (1.0f + expf(-x)); }

__global__ __launch_bounds__(NG, 2)
void decoder_rnn_kernel(const float* __restrict__ h0,
                        const float* __restrict__ c0,
                        const float* __restrict__ tonehot,   // (MAXLEN+1, 1, OUT)
                        const void*  __restrict__ tf_raw,    // bool mask, int8 or int32
                        const float* __restrict__ Wih,       // (4H, OUT)
                        const float* __restrict__ Whh,       // (4H, H)
                        const float* __restrict__ bih,
                        const float* __restrict__ bhh,
                        const float* __restrict__ Wout,      // (OUT, H)
                        const float* __restrict__ bout,
                        float* __restrict__ out)
{
    __shared__ __align__(16) float h_lds[HID];
    __shared__ float gates_lds[NG];
    __shared__ float Wih_lds[OUT * NG];          // transposed: [x][g]
    __shared__ float Wout_lds[OUT * WOUT_STRIDE];
    __shared__ float bout_lds[8];
    __shared__ int   tgt_lds[MAXLEN];
    __shared__ unsigned char tf_lds[MAXLEN];
    __shared__ int   xsel_sh;
    __shared__ int   tf_byte_mode;

    const int g = threadIdx.x;    // gate index 0..511
    const int b = blockIdx.x;     // batch chain

    // ---- W_hh row g into registers (128 VGPRs) ----
    float w[HID];
    {
        const float4* wr = (const float4*)(Whh + (size_t)g * HID);
        #pragma unroll
        for (int k4 = 0; k4 < HID / 4; k4++) {
            float4 v = wr[k4];
            w[4*k4+0] = v.x; w[4*k4+1] = v.y; w[4*k4+2] = v.z; w[4*k4+3] = v.w;
        }
    }
    const float bias_g = bih[g] + bhh[g];

    // ---- W_ih transposed into LDS: Wih_lds[x*NG + g] ----
    #pragma unroll
    for (int x = 0; x < OUT; x++) Wih_lds[x * NG + g] = Wih[g * OUT + x];

    // ---- W_out into LDS with padded stride ----
    for (int idx = g; idx < OUT * HID; idx += NG) {
        int j = idx / HID, k = idx % HID;
        Wout_lds[j * WOUT_STRIDE + k] = Wout[idx];
    }
    if (g < 8) bout_lds[g] = (g < OUT) ? bout[g] : 0.0f;

    // ---- target indices: tgt_next[s] = argmax(onehot[s+1]) ----
    for (int s = g; s < MAXLEN; s += NG) {
        const float* row = tonehot + (size_t)(s + 1) * OUT;
        int idx = 0;
        #pragma unroll
        for (int j = 0; j < OUT; j++) if (row[j] > 0.5f) idx = j;
        tgt_lds[s] = idx;
    }

    // ---- tf_mask layout detection (int8 bool vs int32) ----
    if (g == 0) { tf_byte_mode = 0; xsel_sh = OUT - 1; }  // x0 = one-hot at OUT-1
    __syncthreads();
    {
        const unsigned char* tb = (const unsigned char*)tf_raw;
        int mis = 0;
        for (int p = g; p < MAXLEN; p += NG)          // first 2048 bytes: safe in both layouts
            if ((p & 3) && tb[p]) mis = 1;
        if (mis) atomicOr(&tf_byte_mode, 1);
    }
    // ---- state init ----
    if (g < HID) h_lds[g] = h0[b * HID + g];
    float c_reg = (g < HID) ? c0[b * HID + g] : 0.0f;
    __syncthreads();
    if (tf_byte_mode) {
        const unsigned char* tb = (const unsigned char*)tf_raw;
        for (int s = g; s < MAXLEN; s += NG) tf_lds[s] = (tb[s] != 0);
    } else {
        const int* ti = (const int*)tf_raw;
        for (int s = g; s < MAXLEN; s += NG) tf_lds[s] = (ti[s] != 0);
    }

    float* outlp = out + (size_t)b * MAXLEN * OUT;

    for (int s = 0; s < MAXLEN; s++) {
        __syncthreads();   // A: h_lds, xsel_sh (and setup LDS at s==0) ready
        const int xs = xsel_sh;

        // ---- gates: bias + W_ih[:,xs] + h @ W_hh^T ----
        const float4* h4 = (const float4*)h_lds;
        float a0 = 0.f, a1 = 0.f, a2 = 0.f, a3 = 0.f;
        #pragma unroll
        for (int k4 = 0; k4 < HID / 4; k4++) {
            float4 hv = h4[k4];   // all lanes same address: LDS broadcast
            a0 += hv.x * w[4*k4+0];
            a1 += hv.y * w[4*k4+1];
            a2 += hv.z * w[4*k4+2];
            a3 += hv.w * w[4*k4+3];
        }
        gates_lds[g] = bias_g + Wih_lds[xs * NG + g] + ((a0 + a1) + (a2 + a3));
        __syncthreads();   // B: gates ready

        // ---- LSTM pointwise (threads 0..127), c stays in register ----
        if (g < HID) {
            float ig = gates_lds[g];
            float fg = gates_lds[HID + g];
            float gg = gates_lds[2 * HID + g];
            float og = gates_lds[3 * HID + g];
            float c2 = sigmoidf_(fg) * c_reg + sigmoidf_(ig) * tanhf(gg);
            c_reg = c2;
            float h2 = sigmoidf_(og) * tanhf(c2);
            h_lds[g] = h2;
        }
        __syncthreads();   // C: h2 ready

        // ---- logits + argmax + log_softmax + next input (wave 0) ----
        if (g < 64) {
            const int j = g & 7;        // output class (j==7 is a dummy)
            const int seg = g >> 3;     // k-segment
            float p = 0.f;
            #pragma unroll
            for (int kk = 0; kk < 16; kk++) {
                int k = seg * 16 + kk;
                p += h_lds[k] * Wout_lds[j * WOUT_STRIDE + k];
            }
            p += __shfl_xor(p, 8, 64);
            p += __shfl_xor(p, 16, 64);
            p += __shfl_xor(p, 32, 64);
            float logit = (j < OUT) ? (p + bout_lds[j]) : -INFINITY;

            // argmax, first-index tie-break (matches jnp.argmax)
            float mv = logit; int mi = j;
            #pragma unroll
            for (int d = 1; d < 8; d <<= 1) {
                float ov = __shfl_xor(mv, d, 64);
                int   oi = __shfl_xor(mi, d, 64);
                if (ov > mv || (ov == mv && oi < mi)) { mv = ov; mi = oi; }
            }
            // log-softmax (stable): logit - (max + log(sum exp(logit-max)))
            float e = (j < OUT) ? expf(logit - mv) : 0.0f;
            float ssum = e;
            #pragma unroll
            for (int d = 1; d < 8; d <<= 1) ssum += __shfl_xor(ssum, d, 64);
            float lse = mv + logf(ssum);
            if (g < OUT) outlp[s * OUT + g] = logit - lse;
            if (g == 0)  xsel_sh = tf_lds[s] ? tgt_lds[s] : mi;
        }
    }

    __syncthreads();
    if (g < HID) {
        out[(size_t)BATCH * MAXLEN * OUT + b * HID + g] = h_lds[g];                 // hT
        out[(size_t)BATCH * MAXLEN * OUT + BATCH * HID + b * HID + g] = c_reg;      // cT
    }
}

extern "C" void kernel_launch(void* const* d_in, const int* in_sizes, int n_in,
                              void* d_out, int out_size, void* d_ws, size_t ws_size,
                              hipStream_t stream) {
    const float* h0    = (const float*)d_in[0];
    const float* c0    = (const float*)d_in[1];
    const float* toh   = (const float*)d_in[2];
    const void*  tfm   = (const void*) d_in[3];
    const float* Wih   = (const float*)d_in[4];
    const float* Whh   = (const float*)d_in[5];
    const float* bih   = (const float*)d_in[6];
    const float* bhh   = (const float*)d_in[7];
    const float* Wout  = (const float*)d_in[8];
    const float* bout  = (const float*)d_in[9];
    float* out = (float*)d_out;

    decoder_rnn_kernel<<<dim3(BATCH), dim3(NG), 0, stream>>>(
        h0, c0, toh, tfm, Wih, Whh, bih, bhh, Wout, bout, out);
}